// Round 3
// baseline (23311.588 us; speedup 1.0000x reference)
//
#include <hip/hip_runtime.h>
#include <hip/hip_bf16.h>
#include <stdint.h>

// Problem constants (SequenceDecoder): B=64, LATENT=512, H=1024, V=8192, T=128
#define BB 64
#define LAT 512
#define HH 1024
#define VV 8192
#define TT 128
#define KT 64            // K-tile staged in LDS
#define NW 8             // waves per block
#define BLK (NW * 64)    // 512 threads

// ---------------------------------------------------------------------------
// init: h0 = z @ W_lat.T + b_lat ; c = 0 ; key bootstrap (tok0 = 0)
// grid 32 blocks x 512: block handles 32 rows (j) of h0; wave w rows w*4..w*4+3
// ---------------------------------------------------------------------------
__global__ __launch_bounds__(512) void init_kernel(
    const float* __restrict__ z, const float* __restrict__ W_lat,
    const float* __restrict__ b_lat, float* __restrict__ h0,
    float* __restrict__ c, unsigned long long* __restrict__ key0,
    unsigned long long* __restrict__ key1)
{
    __shared__ float z_lds[BB][KT];
    const int tid = threadIdx.x;
    const int lane = tid & 63;
    const int w = tid >> 6;
    const int rbase = blockIdx.x * 32 + w * 4;   // rows of W_lat / h0 columns

    float acc[4] = {0.f, 0.f, 0.f, 0.f};

    for (int k0 = 0; k0 < LAT; k0 += KT) {
        __syncthreads();
        for (int i = tid; i < BB * KT / 4; i += BLK) {
            int row = i / (KT / 4);
            int g = i % (KT / 4);
            int gs = g ^ (row & 7);
            *(float4*)&z_lds[row][gs * 4] =
                *(const float4*)(z + (size_t)row * LAT + k0 + g * 4);
        }
        __syncthreads();
        const float* wp = W_lat + (size_t)__builtin_amdgcn_readfirstlane(rbase) * LAT + k0;
#pragma unroll
        for (int g = 0; g < KT / 4; ++g) {
            int gs = g ^ (lane & 7);
            float4 zv = *(const float4*)&z_lds[lane][gs * 4];
#pragma unroll
            for (int r = 0; r < 4; ++r) {
                float4 wv = *(const float4*)(wp + (size_t)r * LAT + g * 4);
                acc[r] += zv.x * wv.x + zv.y * wv.y + zv.z * wv.z + zv.w * wv.w;
            }
        }
    }
#pragma unroll
    for (int r = 0; r < 4; ++r) {
        int row = rbase + r;
        h0[(size_t)lane * HH + row] = acc[r] + b_lat[row];
    }
    // zero c  (64*1024 floats over 32 blocks * 512 threads)
    for (int i = blockIdx.x * BLK + tid; i < BB * HH; i += 32 * BLK) c[i] = 0.f;
    // bootstrap keys: key1 low32 = ~0 -> tok = 0
    if (blockIdx.x == 0 && tid < BB) {
        key1[tid] = 0xFFFFFFFFull;
        key0[tid] = 0ull;
    }
}

// ---------------------------------------------------------------------------
// gates + LSTM cell.  grid 128 blocks x 512 threads.
// Block bi owns j in [bi*8, bi*8+8).  Wave w: gate gg=w>>1, j-half jh=w&1,
// 4 j's per wave (acc[4]), lane = batch.  Row of W_ih/W_hh = gg*H + j.
// 128 blocks * 8 j = 1024 j  x  4 gates  = 4096 rows exactly.   <-- bugfix
// Reads tok from key_prev (packed), zeroes key_cur for this step's logits.
// ---------------------------------------------------------------------------
__global__ __launch_bounds__(512) void gates_kernel(
    const float* __restrict__ E, const float* __restrict__ W_ih,
    const float* __restrict__ W_hh, const float* __restrict__ b_ih,
    const float* __restrict__ b_hh, const float* __restrict__ h_prev,
    float* __restrict__ h_next, float* __restrict__ c,
    const unsigned long long* __restrict__ key_prev,
    unsigned long long* __restrict__ key_cur)
{
    __shared__ float x_lds[BB][KT];
    __shared__ float h_lds[BB][KT];
    __shared__ int s_tok[BB];
    __shared__ float g_lds[4][8][BB + 1];

    const int tid = threadIdx.x;
    const int lane = tid & 63;
    const int w = tid >> 6;
    const int jbase = blockIdx.x * 8;
    const int gg = w >> 1;
    const int jh = w & 1;

    if (blockIdx.x == 0 && tid < BB) key_cur[tid] = 0ull;
    if (tid < BB)
        s_tok[tid] = (int)(~(unsigned int)(key_prev[tid] & 0xFFFFFFFFull));

    float acc[4] = {0.f, 0.f, 0.f, 0.f};

    const int r0 = gg * HH + jbase + jh * 4;   // wave-uniform base row, max 4095

    for (int k0 = 0; k0 < HH; k0 += KT) {
        __syncthreads();   // covers s_tok on iter 0, LDS reuse afterwards
        for (int i = tid; i < BB * KT / 4; i += BLK) {
            int row = i / (KT / 4);
            int g = i % (KT / 4);
            int gs = g ^ (row & 7);
            float4 xv = *(const float4*)(E + (size_t)s_tok[row] * HH + k0 + g * 4);
            float4 hv = *(const float4*)(h_prev + (size_t)row * HH + k0 + g * 4);
            *(float4*)&x_lds[row][gs * 4] = xv;
            *(float4*)&h_lds[row][gs * 4] = hv;
        }
        __syncthreads();

        const float* wih = W_ih + (size_t)__builtin_amdgcn_readfirstlane(r0) * HH + k0;
        const float* whh = W_hh + (size_t)__builtin_amdgcn_readfirstlane(r0) * HH + k0;
#pragma unroll
        for (int g = 0; g < KT / 4; ++g) {
            int gs = g ^ (lane & 7);
            float4 xv = *(const float4*)&x_lds[lane][gs * 4];
            float4 hv = *(const float4*)&h_lds[lane][gs * 4];
#pragma unroll
            for (int jj = 0; jj < 4; ++jj) {
                float4 wi = *(const float4*)(wih + (size_t)jj * HH + g * 4);
                float4 wh = *(const float4*)(whh + (size_t)jj * HH + g * 4);
                acc[jj] += xv.x * wi.x + xv.y * wi.y + xv.z * wi.z + xv.w * wi.w
                         + hv.x * wh.x + hv.y * wh.y + hv.z * wh.z + hv.w * wh.w;
            }
        }
    }

    // deposit gate pre-activations (+ biases) into LDS for the cell update
#pragma unroll
    for (int jj = 0; jj < 4; ++jj) {
        int r = r0 + jj;
        g_lds[gg][jh * 4 + jj][lane] = acc[jj] + b_ih[r] + b_hh[r];
    }
    __syncthreads();

    // LSTM cell: 8 j x 64 b = 512 items, one per thread
    {
        int item = tid;
        int b_ = item >> 3;
        int jl = item & 7;
        int j = jbase + jl;
        float iv = g_lds[0][jl][b_];
        float fv = g_lds[1][jl][b_];
        float gv = g_lds[2][jl][b_];
        float ov = g_lds[3][jl][b_];
        iv = 1.f / (1.f + expf(-iv));
        fv = 1.f / (1.f + expf(-fv));
        gv = tanhf(gv);
        ov = 1.f / (1.f + expf(-ov));
        size_t idx = (size_t)b_ * HH + j;
        float cn = fv * c[idx] + iv * gv;
        c[idx] = cn;
        h_next[idx] = ov * tanhf(cn);
    }
}

// ---------------------------------------------------------------------------
// logits + store + argmax.  grid 256 blocks x 512 threads.
// Block bi owns rows [bi*32, bi*32+32); wave w rows w*4..w*4+3; lane = batch.
// Argmax via packed (orderable_float << 32 | ~row) u64 atomicMax.
// ---------------------------------------------------------------------------
__global__ __launch_bounds__(512) void logits_kernel(
    const float* __restrict__ h, const float* __restrict__ W_out,
    const float* __restrict__ b_out, float* __restrict__ out, int t,
    unsigned long long* __restrict__ key_cur)
{
    __shared__ float h_lds[BB][KT];
    __shared__ unsigned long long red[NW][BB];

    const int tid = threadIdx.x;
    const int lane = tid & 63;
    const int w = tid >> 6;
    const int rbase = blockIdx.x * 32 + w * 4;

    float acc[4] = {0.f, 0.f, 0.f, 0.f};

    for (int k0 = 0; k0 < HH; k0 += KT) {
        __syncthreads();
        for (int i = tid; i < BB * KT / 4; i += BLK) {
            int row = i / (KT / 4);
            int g = i % (KT / 4);
            int gs = g ^ (row & 7);
            *(float4*)&h_lds[row][gs * 4] =
                *(const float4*)(h + (size_t)row * HH + k0 + g * 4);
        }
        __syncthreads();
        const float* wp = W_out + (size_t)__builtin_amdgcn_readfirstlane(rbase) * HH + k0;
#pragma unroll
        for (int g = 0; g < KT / 4; ++g) {
            int gs = g ^ (lane & 7);
            float4 hv = *(const float4*)&h_lds[lane][gs * 4];
#pragma unroll
            for (int r = 0; r < 4; ++r) {
                float4 wv = *(const float4*)(wp + (size_t)r * HH + g * 4);
                acc[r] += hv.x * wv.x + hv.y * wv.y + hv.z * wv.z + hv.w * wv.w;
            }
        }
    }

    unsigned long long best = 0ull;
#pragma unroll
    for (int r = 0; r < 4; ++r) {
        int row = rbase + r;
        float v = acc[r] + b_out[row];
        out[(size_t)lane * TT * VV + (size_t)t * VV + row] = v;
        unsigned int ub = __float_as_uint(v);
        unsigned int key32 = (ub & 0x80000000u) ? ~ub : (ub | 0x80000000u);
        unsigned long long key =
            ((unsigned long long)key32 << 32) | (unsigned long long)(~(unsigned int)row);
        best = best > key ? best : key;
    }
    red[w][lane] = best;
    __syncthreads();
    if (w == 0) {
        unsigned long long m = red[0][lane];
#pragma unroll
        for (int ww = 1; ww < NW; ++ww) {
            unsigned long long v = red[ww][lane];
            m = m > v ? m : v;
        }
        atomicMax(&key_cur[lane], m);
    }
}

// ---------------------------------------------------------------------------
extern "C" void kernel_launch(void* const* d_in, const int* in_sizes, int n_in,
                              void* d_out, int out_size, void* d_ws, size_t ws_size,
                              hipStream_t stream)
{
    const float* z     = (const float*)d_in[0];
    const float* E     = (const float*)d_in[1];
    const float* W_ih  = (const float*)d_in[2];
    const float* W_hh  = (const float*)d_in[3];
    const float* b_ih  = (const float*)d_in[4];
    const float* b_hh  = (const float*)d_in[5];
    const float* W_lat = (const float*)d_in[6];
    const float* b_lat = (const float*)d_in[7];
    const float* W_out = (const float*)d_in[8];
    const float* b_out = (const float*)d_in[9];
    float* out = (float*)d_out;

    // workspace layout
    float* h_bufs = (float*)d_ws;                 // 2 * 64 * 1024 f32
    float* c      = h_bufs + 2 * BB * HH;         // 64 * 1024 f32
    unsigned long long* keys = (unsigned long long*)(c + BB * HH);  // 2 * 64 u64

    init_kernel<<<32, BLK, 0, stream>>>(z, W_lat, b_lat, h_bufs, c, keys, keys + BB);

    for (int t = 0; t < TT; ++t) {
        int p = t & 1;
        const float* hp = h_bufs + p * BB * HH;        // h(t-1)
        float* hn       = h_bufs + (1 - p) * BB * HH;  // h(t)
        gates_kernel<<<128, BLK, 0, stream>>>(E, W_ih, W_hh, b_ih, b_hh,
                                              hp, hn, c,
                                              keys + (1 - p) * BB,   // tok in
                                              keys + p * BB);        // zero for logits(t)
        logits_kernel<<<256, BLK, 0, stream>>>(hn, W_out, b_out, out, t,
                                               keys + p * BB);
    }
}

// Round 4
// 5814.286 us; speedup vs baseline: 4.0094x; 4.0094x over previous
//
#include <hip/hip_runtime.h>
#include <hip/hip_bf16.h>
#include <stdint.h>

// SequenceDecoder: B=64, LATENT=512, H=1024, V=8192, T=128
#define BB 64
#define LAT 512
#define HH 1024
#define VV 8192
#define TT 128

typedef short bf16x8 __attribute__((ext_vector_type(8)));
typedef float f32x4 __attribute__((ext_vector_type(4)));
typedef unsigned long long u64;

__device__ __forceinline__ unsigned short f2bf(float f) {
    union { float f; unsigned int u; } a; a.f = f;
    unsigned int u = a.u;
    unsigned int r = u + 0x7FFFu + ((u >> 16) & 1u);   // RNE
    return (unsigned short)(r >> 16);
}
__device__ __forceinline__ float bf2f(unsigned short b) {
    union { unsigned int u; float f; } a; a.u = ((unsigned int)b) << 16;
    return a.f;
}

// ---------------------------------------------------------------------------
// split fp32 -> (hi, lo) bf16.  n4 = n/4 float4 groups.
// ---------------------------------------------------------------------------
__global__ __launch_bounds__(256) void split_kernel(
    const float* __restrict__ src, unsigned short* __restrict__ hi,
    unsigned short* __restrict__ lo, int n4)
{
    int i = blockIdx.x * 256 + threadIdx.x;
    if (i >= n4) return;
    float4 v = ((const float4*)src)[i];
    ushort4 h, l;
    h.x = f2bf(v.x); l.x = f2bf(v.x - bf2f(h.x));
    h.y = f2bf(v.y); l.y = f2bf(v.y - bf2f(h.y));
    h.z = f2bf(v.z); l.z = f2bf(v.z - bf2f(h.z));
    h.w = f2bf(v.w); l.w = f2bf(v.w - bf2f(h.w));
    ((ushort4*)hi)[i] = h;
    ((ushort4*)lo)[i] = l;
}

// ---------------------------------------------------------------------------
// init: h0 = z @ W_lat.T + b_lat (fp32 VALU, tiny) -> split store; c=0;
// partials: set1 shard0 = 0xFFFFFFFF (tok=0), everything else 0.
// grid 32 x 512
// ---------------------------------------------------------------------------
__global__ __launch_bounds__(512) void init_kernel(
    const float* __restrict__ z, const float* __restrict__ W_lat,
    const float* __restrict__ b_lat, unsigned short* __restrict__ h0_hi,
    unsigned short* __restrict__ h0_lo, float* __restrict__ c,
    u64* __restrict__ parts)
{
    __shared__ float z_lds[BB][64];
    const int tid = threadIdx.x;
    const int lane = tid & 63;
    const int w = tid >> 6;
    const int rbase = blockIdx.x * 32 + w * 4;

    float acc[4] = {0.f, 0.f, 0.f, 0.f};
    for (int k0 = 0; k0 < LAT; k0 += 64) {
        __syncthreads();
        for (int i = tid; i < BB * 16; i += 512) {
            int row = i / 16, g = i % 16, gs = g ^ (row & 7);
            *(float4*)&z_lds[row][gs * 4] =
                *(const float4*)(z + (size_t)row * LAT + k0 + g * 4);
        }
        __syncthreads();
        const float* wp = W_lat + (size_t)__builtin_amdgcn_readfirstlane(rbase) * LAT + k0;
#pragma unroll
        for (int g = 0; g < 16; ++g) {
            int gs = g ^ (lane & 7);
            float4 zv = *(const float4*)&z_lds[lane][gs * 4];
#pragma unroll
            for (int r = 0; r < 4; ++r) {
                float4 wv = *(const float4*)(wp + (size_t)r * LAT + g * 4);
                acc[r] += zv.x * wv.x + zv.y * wv.y + zv.z * wv.z + zv.w * wv.w;
            }
        }
    }
#pragma unroll
    for (int r = 0; r < 4; ++r) {
        int row = rbase + r;
        float hv = acc[r] + b_lat[row];
        unsigned short hb = f2bf(hv);
        h0_hi[(size_t)lane * HH + row] = hb;
        h0_lo[(size_t)lane * HH + row] = f2bf(hv - bf2f(hb));
    }
    for (int i = blockIdx.x * 512 + tid; i < BB * HH; i += 32 * 512) c[i] = 0.f;
    // partials: 2 sets x 16 shards x 64 b.  set1 (read by gates t=0) shard0 = ~0u.
    int gid = blockIdx.x * 512 + tid;
    if (gid < 2048)
        parts[gid] = (gid >= 1024 && gid < 1088) ? 0xFFFFFFFFull : 0ull;
}

// ---------------------------------------------------------------------------
// gates (MFMA) + LSTM cell.  grid 256 x 512 (8 waves).
// Block owns 16 W-rows: row_map[m] = (m>>2)*H + blockIdx*4 + (m&3)
//   (gate = m>>2, jj = m&3)  -> all 4 gates of 4 j's stay in-block for the cell.
// Wave w: bt = w&3 (batch tile of 16), p = w>>2 (K-parity half).
// Weights LDS-staged per 256-K chunk (XOR-swizzled); acts read from L2.
// 3-product split: hi*hi + hi*lo + lo*hi per weight matrix.
// ---------------------------------------------------------------------------
__global__ __launch_bounds__(512) void gates_mfma(
    const unsigned short* __restrict__ E_hi, const unsigned short* __restrict__ E_lo,
    const unsigned short* __restrict__ Wih_hi, const unsigned short* __restrict__ Wih_lo,
    const unsigned short* __restrict__ Whh_hi, const unsigned short* __restrict__ Whh_lo,
    const float* __restrict__ b_ih, const float* __restrict__ b_hh,
    const unsigned short* __restrict__ hp_hi, const unsigned short* __restrict__ hp_lo,
    unsigned short* __restrict__ hn_hi, unsigned short* __restrict__ hn_lo,
    float* __restrict__ c,
    const u64* __restrict__ part_r, u64* __restrict__ part_z)
{
    __shared__ char wlds[32768];          // 4 arrays x [16 rows][256 k] bf16
    __shared__ float g_sum[16][66];

    const int tid = threadIdx.x;
    const int lane = tid & 63;
    const int w = tid >> 6;
    const int bt = w & 3;
    const int p = w >> 2;
    const int jbase4 = blockIdx.x * 4;

    // zero the partials set this step's logits will atomicMax into
    if (blockIdx.x < 16 && tid < 64) part_z[blockIdx.x * 64 + tid] = 0ull;

    // per-lane token for b = bt*16 + (lane&15): max over 16 shards
    const int b_l = bt * 16 + (lane & 15);
    u64 mk = 0;
#pragma unroll
    for (int s = 0; s < 16; ++s) {
        u64 k = part_r[s * 64 + b_l];
        mk = mk > k ? mk : k;
    }
    const int tok = ((int)(~(unsigned int)(mk & 0xFFFFFFFFull))) & (VV - 1);

    const unsigned short* xrow_hi = E_hi + (size_t)tok * HH;
    const unsigned short* xrow_lo = E_lo + (size_t)tok * HH;
    const unsigned short* hrow_hi = hp_hi + (size_t)b_l * HH;
    const unsigned short* hrow_lo = hp_lo + (size_t)b_l * HH;

    f32x4 acc = {0.f, 0.f, 0.f, 0.f};
    const int lrow = lane & 15;
    const int kgrp = lane >> 4;

    for (int kc = 0; kc < 4; ++kc) {
        const int kc0 = kc * 256;
        __syncthreads();
#pragma unroll
        for (int it = 0; it < 4; ++it) {
            int g = it * 512 + tid;        // 2048 granules of 16B
            int arr = g >> 9;              // 0..3: ih_hi, ih_lo, hh_hi, hh_lo
            int row = (g >> 5) & 15;
            int kg = g & 31;
            int row_g = (row >> 2) * HH + jbase4 + (row & 3);
            const unsigned short* src = (arr == 0) ? Wih_hi : (arr == 1) ? Wih_lo
                                      : (arr == 2) ? Whh_hi : Whh_lo;
            ulonglong2 v = *(const ulonglong2*)(src + (size_t)row_g * HH + kc0 + kg * 8);
            int off = arr * 8192 + ((row * 512 + kg * 16) ^ ((row & 7) << 4));
            *(ulonglong2*)(wlds + off) = v;
        }
        __syncthreads();

#pragma unroll
        for (int i = 0; i < 4; ++i) {
            int koff = (2 * i + p) * 32 + kgrp * 8;    // local k (this wave's parity)
            int abyte = (lrow * 512 + koff * 2) ^ ((lrow & 7) << 4);
            bf16x8 a_ih_hi = *(const bf16x8*)(wlds + abyte);
            bf16x8 a_ih_lo = *(const bf16x8*)(wlds + 8192 + abyte);
            bf16x8 a_hh_hi = *(const bf16x8*)(wlds + 16384 + abyte);
            bf16x8 a_hh_lo = *(const bf16x8*)(wlds + 24576 + abyte);
            int gk = kc0 + koff;
            bf16x8 xv_hi = *(const bf16x8*)(xrow_hi + gk);
            bf16x8 xv_lo = *(const bf16x8*)(xrow_lo + gk);
            bf16x8 hv_hi = *(const bf16x8*)(hrow_hi + gk);
            bf16x8 hv_lo = *(const bf16x8*)(hrow_lo + gk);
            acc = __builtin_amdgcn_mfma_f32_16x16x32_bf16(a_ih_hi, xv_hi, acc, 0, 0, 0);
            acc = __builtin_amdgcn_mfma_f32_16x16x32_bf16(a_ih_hi, xv_lo, acc, 0, 0, 0);
            acc = __builtin_amdgcn_mfma_f32_16x16x32_bf16(a_ih_lo, xv_hi, acc, 0, 0, 0);
            acc = __builtin_amdgcn_mfma_f32_16x16x32_bf16(a_hh_hi, hv_hi, acc, 0, 0, 0);
            acc = __builtin_amdgcn_mfma_f32_16x16x32_bf16(a_hh_hi, hv_lo, acc, 0, 0, 0);
            acc = __builtin_amdgcn_mfma_f32_16x16x32_bf16(a_hh_lo, hv_hi, acc, 0, 0, 0);
        }
    }

    // parity-pair reduce (p=1 stores, p=0 adds + bias), then cell update
    if (p == 1) {
#pragma unroll
        for (int r = 0; r < 4; ++r)
            g_sum[kgrp * 4 + r][b_l] = acc[r];
    }
    __syncthreads();
    if (p == 0) {
#pragma unroll
        for (int r = 0; r < 4; ++r) {
            int m = kgrp * 4 + r;
            int row_g = (m >> 2) * HH + jbase4 + (m & 3);
            g_sum[m][b_l] += acc[r] + b_ih[row_g] + b_hh[row_g];
        }
    }
    __syncthreads();
    if (tid < 256) {
        int jj = tid >> 6;
        int b_ = tid & 63;
        float iv = g_sum[jj][b_];
        float fv = g_sum[4 + jj][b_];
        float gv = g_sum[8 + jj][b_];
        float ov = g_sum[12 + jj][b_];
        iv = 1.f / (1.f + expf(-iv));
        fv = 1.f / (1.f + expf(-fv));
        gv = tanhf(gv);
        ov = 1.f / (1.f + expf(-ov));
        size_t idx = (size_t)b_ * HH + jbase4 + jj;
        float cn = fv * c[idx] + iv * gv;
        c[idx] = cn;
        float hn = ov * tanhf(cn);
        unsigned short hb = f2bf(hn);
        hn_hi[idx] = hb;
        hn_lo[idx] = f2bf(hn - bf2f(hb));
    }
}

// ---------------------------------------------------------------------------
// logits (MFMA) + store + argmax.  grid 256 x 512 (8 waves).
// Block owns v-rows [bi*32, bi*32+32).  Wave w: bt = w&3, rt = w>>2.
// ---------------------------------------------------------------------------
__global__ __launch_bounds__(512) void logits_mfma(
    const unsigned short* __restrict__ h_hi, const unsigned short* __restrict__ h_lo,
    const unsigned short* __restrict__ Wout_hi, const unsigned short* __restrict__ Wout_lo,
    const float* __restrict__ b_out, float* __restrict__ out, int t,
    u64* __restrict__ part_w)
{
    __shared__ char wlds[32768];          // 2 arrays x [32 rows][256 k] bf16

    const int tid = threadIdx.x;
    const int lane = tid & 63;
    const int w = tid >> 6;
    const int bt = w & 3;
    const int rt = w >> 2;
    const int rbase = blockIdx.x * 32;
    const int b_l = bt * 16 + (lane & 15);
    const int lrow = lane & 15;
    const int kgrp = lane >> 4;

    const unsigned short* hr_hi = h_hi + (size_t)b_l * HH;
    const unsigned short* hr_lo = h_lo + (size_t)b_l * HH;

    f32x4 acc = {0.f, 0.f, 0.f, 0.f};

    for (int kc = 0; kc < 4; ++kc) {
        const int kc0 = kc * 256;
        __syncthreads();
#pragma unroll
        for (int it = 0; it < 4; ++it) {
            int g = it * 512 + tid;        // 2048 granules
            int arr = g >> 10;             // 0..1: hi, lo
            int row = (g >> 5) & 31;
            int kg = g & 31;
            const unsigned short* src = arr ? Wout_lo : Wout_hi;
            ulonglong2 v = *(const ulonglong2*)(src + (size_t)(rbase + row) * HH + kc0 + kg * 8);
            int off = arr * 16384 + ((row * 512 + kg * 16) ^ ((row & 7) << 4));
            *(ulonglong2*)(wlds + off) = v;
        }
        __syncthreads();

#pragma unroll
        for (int i = 0; i < 8; ++i) {
            int koff = i * 32 + kgrp * 8;
            int arow = rt * 16 + lrow;
            int abyte = (arow * 512 + koff * 2) ^ ((arow & 7) << 4);
            bf16x8 w_hi = *(const bf16x8*)(wlds + abyte);
            bf16x8 w_lo = *(const bf16x8*)(wlds + 16384 + abyte);
            int gk = kc0 + koff;
            bf16x8 hv_hi = *(const bf16x8*)(hr_hi + gk);
            bf16x8 hv_lo = *(const bf16x8*)(hr_lo + gk);
            acc = __builtin_amdgcn_mfma_f32_16x16x32_bf16(w_hi, hv_hi, acc, 0, 0, 0);
            acc = __builtin_amdgcn_mfma_f32_16x16x32_bf16(w_hi, hv_lo, acc, 0, 0, 0);
            acc = __builtin_amdgcn_mfma_f32_16x16x32_bf16(w_lo, hv_hi, acc, 0, 0, 0);
        }
    }

    // bias + store + argmax keys
    const int v0 = rbase + rt * 16 + kgrp * 4;
    float4 bo = *(const float4*)(b_out + v0);
    f32x4 res;
    res[0] = acc[0] + bo.x; res[1] = acc[1] + bo.y;
    res[2] = acc[2] + bo.z; res[3] = acc[3] + bo.w;
    *(f32x4*)(out + (size_t)b_l * TT * VV + (size_t)t * VV + v0) = res;

    u64 best = 0ull;
#pragma unroll
    for (int r = 0; r < 4; ++r) {
        unsigned int row = (unsigned int)(v0 + r);
        union { float f; unsigned int u; } a; a.f = res[r];
        unsigned int ub = a.u;
        unsigned int key32 = (ub & 0x80000000u) ? ~ub : (ub | 0x80000000u);
        u64 key = ((u64)key32 << 32) | (u64)(~row);
        best = best > key ? best : key;
    }
    u64 o = __shfl_xor(best, 16);  best = best > o ? best : o;
    o = __shfl_xor(best, 32);      best = best > o ? best : o;
    if ((lane & 48) == 0)   // lanes 0..15 hold the wave-combined key for their b
        atomicMax(&part_w[(blockIdx.x & 15) * 64 + b_l], best);
}

// ---------------------------------------------------------------------------
extern "C" void kernel_launch(void* const* d_in, const int* in_sizes, int n_in,
                              void* d_out, int out_size, void* d_ws, size_t ws_size,
                              hipStream_t stream)
{
    const float* z     = (const float*)d_in[0];
    const float* E     = (const float*)d_in[1];
    const float* W_ih  = (const float*)d_in[2];
    const float* W_hh  = (const float*)d_in[3];
    const float* b_ih  = (const float*)d_in[4];
    const float* b_hh  = (const float*)d_in[5];
    const float* W_lat = (const float*)d_in[6];
    const float* b_lat = (const float*)d_in[7];
    const float* W_out = (const float*)d_in[8];
    const float* b_out = (const float*)d_in[9];
    float* out = (float*)d_out;

    // workspace carve (ushort units from base)
    unsigned short* us = (unsigned short*)d_ws;
    unsigned short* E_hi    = us;                       // 8388608
    unsigned short* E_lo    = us + 8388608;
    unsigned short* Wih_hi  = us + 16777216;            // 4194304
    unsigned short* Wih_lo  = us + 20971520;
    unsigned short* Whh_hi  = us + 25165824;
    unsigned short* Whh_lo  = us + 29360128;
    unsigned short* Wout_hi = us + 33554432;            // 8388608
    unsigned short* Wout_lo = us + 41943040;
    unsigned short* h_hi    = us + 50331648;            // 2 x 65536
    unsigned short* h_lo    = us + 50462720;
    float*          c       = (float*)(us + 50593792);  // 65536 f32
    u64*            parts   = (u64*)(us + 50724864);    // 2 x 1024 u64

    split_kernel<<<8192, 256, 0, stream>>>(E,     E_hi,    E_lo,    VV * HH / 4);
    split_kernel<<<4096, 256, 0, stream>>>(W_ih,  Wih_hi,  Wih_lo,  4 * HH * HH / 4);
    split_kernel<<<4096, 256, 0, stream>>>(W_hh,  Whh_hi,  Whh_lo,  4 * HH * HH / 4);
    split_kernel<<<8192, 256, 0, stream>>>(W_out, Wout_hi, Wout_lo, VV * HH / 4);

    init_kernel<<<32, 512, 0, stream>>>(z, W_lat, b_lat, h_hi, h_lo, c, parts);

    for (int t = 0; t < TT; ++t) {
        int hp = t & 1;                   // h set read by gates(t)
        int hn = 1 - hp;                  // h set written by gates(t)
        u64* rd = parts + ((t + 1) & 1) * 1024;  // written by logits(t-1) / init
        u64* zw = parts + (t & 1) * 1024;        // to be written by logits(t)
        gates_mfma<<<256, 512, 0, stream>>>(
            E_hi, E_lo, Wih_hi, Wih_lo, Whh_hi, Whh_lo, b_ih, b_hh,
            h_hi + hp * 65536, h_lo + hp * 65536,
            h_hi + hn * 65536, h_lo + hn * 65536,
            c, rd, zw);
        logits_mfma<<<256, 512, 0, stream>>>(
            h_hi + hn * 65536, h_lo + hn * 65536,
            Wout_hi, Wout_lo, b_out, out, t, zw);
    }
}